// Round 3
// baseline (195.162 us; speedup 1.0000x reference)
//
#include <hip/hip_runtime.h>

#define B_ 4
#define S_ 2048
#define HIDN 512
#define NH 8
#define DH 64

typedef __attribute__((ext_vector_type(8))) short short8;
typedef __attribute__((ext_vector_type(4))) short short4v;
typedef __attribute__((ext_vector_type(8))) __bf16 bf16x8;
typedef __attribute__((ext_vector_type(4))) float floatx4;
typedef __attribute__((ext_vector_type(2))) unsigned uint2v;
typedef __attribute__((ext_vector_type(4))) unsigned uint4v;

__device__ inline short f2bf(float f) {            // RTNE
    union { float f; unsigned u; } x; x.f = f;
    unsigned r = x.u + 0x7fffu + ((x.u >> 16) & 1u);
    return (short)(r >> 16);
}

// pack two floats -> two bf16 (round-half-up) in one uint via v_perm
__device__ inline unsigned pack2(float a, float b) {
    unsigned ua = __builtin_bit_cast(unsigned, a) + 0x8000u;
    unsigned ub = __builtin_bit_cast(unsigned, b) + 0x8000u;
    return __builtin_amdgcn_perm(ub, ua, 0x07060302);  // shorts [a, b]
}

// 8 fp32 -> 8 bf16 (12 VALU)
__device__ inline short8 cvt8(const float* __restrict__ p) {
    floatx4 f0 = *(const floatx4*)p;
    floatx4 f1 = *(const floatx4*)(p + 4);
    uint4v u;
    u[0] = pack2(f0[0], f0[1]); u[1] = pack2(f0[2], f0[3]);
    u[2] = pack2(f1[0], f1[1]); u[3] = pack2(f1[2], f1[3]);
    return __builtin_bit_cast(short8, u);
}

__device__ inline floatx4 mfma_s(short8 a, short8 b, floatx4 c) {
    return __builtin_amdgcn_mfma_f32_16x16x32_bf16(
        __builtin_bit_cast(bf16x8, a), __builtin_bit_cast(bf16x8, b), c, 0, 0, 0);
}

__device__ inline float vmax4(floatx4 v) {
    return fmaxf(fmaxf(v[0], v[1]), fmaxf(v[2], v[3]));
}

// ---------------------------------------------------------------------------
// Pre-convert Wq,Wk,Wv (fp32 -> bf16). grid (256,3) x 256 thr, 4 elem/thr.
// ---------------------------------------------------------------------------
__global__ void cvt_w(const float* __restrict__ wq, const float* __restrict__ wk,
                      const float* __restrict__ wv, short* __restrict__ out) {
    const float* src = blockIdx.y == 0 ? wq : (blockIdx.y == 1 ? wk : wv);
    int i = (blockIdx.x * 256 + threadIdx.x) * 4;
    floatx4 f = *(const floatx4*)&src[i];
    short4v v; v[0]=f2bf(f[0]); v[1]=f2bf(f[1]); v[2]=f2bf(f[2]); v[3]=f2bf(f[3]);
    *(short4v*)&out[blockIdx.y * (HIDN * HIDN) + i] = v;
}

// ---------------------------------------------------------------------------
// Fused QKV projection. grid (64,4,3); z=0:Q, z=1:K (head layout), z=2:V^T.
// ---------------------------------------------------------------------------
__global__ __launch_bounds__(256) void gemm_qkv(const float* __restrict__ xq,
                                                const float* __restrict__ xk,
                                                const float* __restrict__ xv,
                                                const short* __restrict__ wb,
                                                short* __restrict__ Qh,
                                                short* __restrict__ Kh,
                                                short* __restrict__ VT) {
    const int z = blockIdx.z;
    const float* X = z == 0 ? xq : (z == 1 ? xk : xv);
    const short* W = wb + z * (HIDN * HIDN);
    short* dstQK = z == 0 ? Qh : Kh;

    __shared__ __align__(16) short Als[128][72];   // 64 cols + pad to 72
    __shared__ __align__(16) short Bls[128][72];

    const int t = threadIdx.x;
    const int w = t >> 6, lane = t & 63, quad = lane >> 4, l16 = lane & 15;
    const int wm = (w & 1) * 64, wn = (w >> 1) * 64;
    const int m0 = blockIdx.x * 128, n0 = blockIdx.y * 128;

    floatx4 acc[4][4];
    floatx4 zero = {0.f, 0.f, 0.f, 0.f};
#pragma unroll
    for (int i = 0; i < 4; i++)
#pragma unroll
        for (int j = 0; j < 4; j++) acc[i][j] = zero;

    const int row0 = t >> 3;        // 0..31
    const int c8 = (t & 7) * 8;     // 0..56

    for (int k0 = 0; k0 < HIDN; k0 += 64) {
        __syncthreads();
#pragma unroll
        for (int rr = 0; rr < 4; rr++)
            *(short8*)&Als[row0 + rr*32][c8] =
                cvt8(&X[(m0 + row0 + rr*32) * HIDN + k0 + c8]);
#pragma unroll
        for (int rr = 0; rr < 4; rr++)
            *(short8*)&Bls[row0 + rr*32][c8] =
                *(const short8*)&W[(n0 + row0 + rr*32) * HIDN + k0 + c8];
        __syncthreads();

#pragma unroll
        for (int ks = 0; ks < 2; ks++) {
            const int cq8 = (ks * 4 + quad) * 8;
            short8 a[4], b[4];
#pragma unroll
            for (int i = 0; i < 4; i++)
                a[i] = *(const short8*)&Als[wm + i*16 + l16][cq8];
#pragma unroll
            for (int j = 0; j < 4; j++)
                b[j] = *(const short8*)&Bls[wn + j*16 + l16][cq8];
#pragma unroll
            for (int i = 0; i < 4; i++)
#pragma unroll
                for (int j = 0; j < 4; j++)
                    acc[i][j] = mfma_s(a[i], b[j], acc[i][j]);
        }
    }

    if (z < 2) {   // head layout (B,NH,S,DH)
#pragma unroll
        for (int i = 0; i < 4; i++)
#pragma unroll
            for (int j = 0; j < 4; j++)
#pragma unroll
                for (int r = 0; r < 4; r++) {
                    int m = m0 + wm + i*16 + quad*4 + r;
                    int n = n0 + wn + j*16 + l16;
                    int bb = m >> 11, s = m & 2047, h = n >> 6, d = n & 63;
                    dstQK[((bb * NH + h) * S_ + s) * DH + d] = f2bf(acc[i][j][r]);
                }
    } else {       // V^T (B,NH,DH,S)
#pragma unroll
        for (int i = 0; i < 4; i++)
#pragma unroll
            for (int j = 0; j < 4; j++) {
                int s0 = m0 + wm + i*16 + quad*4;
                int n = n0 + wn + j*16 + l16;
                int bb = s0 >> 11, s = s0 & 2047, h = n >> 6, d = n & 63;
                uint2v v;
                v[0] = pack2(acc[i][j][0], acc[i][j][1]);
                v[1] = pack2(acc[i][j][2], acc[i][j][3]);
                *(uint2v*)&VT[((bb * NH + h) * DH + d) * S_ + s] = v;
            }
    }
}

// ---------------------------------------------------------------------------
// Out projection. 128x64 tile, grid(64,8), BK=64 padded. AO bf16, Wo fp32
// cvt in staging, out fp32.
// ---------------------------------------------------------------------------
__global__ __launch_bounds__(256) void gemm_out(const short* __restrict__ AO,
                                                const float* __restrict__ Wo,
                                                float* __restrict__ C) {
    __shared__ __align__(16) short Als[128][72];
    __shared__ __align__(16) short Bls[64][72];

    const int t = threadIdx.x;
    const int w = t >> 6, lane = t & 63, quad = lane >> 4, l16 = lane & 15;
    const int wm = (w & 1) * 64, wn = (w >> 1) * 32;
    const int m0 = blockIdx.x * 128, n0 = blockIdx.y * 64;

    floatx4 acc[4][2];
    floatx4 zero = {0.f, 0.f, 0.f, 0.f};
#pragma unroll
    for (int i = 0; i < 4; i++)
#pragma unroll
        for (int j = 0; j < 2; j++) acc[i][j] = zero;

    const int row0 = t >> 3;        // 0..31
    const int c8 = (t & 7) * 8;     // 0..56

    for (int k0 = 0; k0 < HIDN; k0 += 64) {
        __syncthreads();
#pragma unroll
        for (int rr = 0; rr < 4; rr++)
            *(short8*)&Als[row0 + rr*32][c8] =
                *(const short8*)&AO[(m0 + row0 + rr*32) * HIDN + k0 + c8];
#pragma unroll
        for (int rr = 0; rr < 2; rr++)
            *(short8*)&Bls[row0 + rr*32][c8] =
                cvt8(&Wo[(n0 + row0 + rr*32) * HIDN + k0 + c8]);
        __syncthreads();

#pragma unroll
        for (int ks = 0; ks < 2; ks++) {
            const int cq8 = (ks * 4 + quad) * 8;
            short8 a[4], b[2];
#pragma unroll
            for (int i = 0; i < 4; i++)
                a[i] = *(const short8*)&Als[wm + i*16 + l16][cq8];
#pragma unroll
            for (int j = 0; j < 2; j++)
                b[j] = *(const short8*)&Bls[wn + j*16 + l16][cq8];
#pragma unroll
            for (int i = 0; i < 4; i++)
#pragma unroll
                for (int j = 0; j < 2; j++)
                    acc[i][j] = mfma_s(a[i], b[j], acc[i][j]);
        }
    }

#pragma unroll
    for (int i = 0; i < 4; i++)
#pragma unroll
        for (int j = 0; j < 2; j++)
#pragma unroll
            for (int r = 0; r < 4; r++) {
                int m = m0 + wm + i*16 + quad*4 + r;
                int n = n0 + wn + j*16 + l16;
                C[m * HIDN + n] = acc[i][j][r];
            }
}

// ---------------------------------------------------------------------------
// Flash attention, round-7: KEY-SPLIT ACROSS 2 WAVE-GROUPS (512 threads).
// Group g (4 waves) processes tiles 2i+g with its own K/V LDS region and its
// own online-softmax state (m,l,O); partials merged in-block at the end via
// LDS (no extra workspace, no combine kernel). Halves the serial tile chain
// for long-vl blocks (the measured tail), keeps 16 waves/CU (64 KB LDS ->
// 2 blocks/CU). Per-tile body is the proven round-0 code: reg-staged
// XOR-swizzled LDS, S^T = K·Q^T, wave-local P overlay (lgkmcnt fence, no
// 4th barrier), exp2-domain softmax with fused scale + norescale skip.
// ---------------------------------------------------------------------------
__global__ __launch_bounds__(512, 4) void attn_kernel(const short* __restrict__ Qh,
                                                      const short* __restrict__ Kh,
                                                      const short* __restrict__ VT,
                                                      const int* __restrict__ vlen,
                                                      short* __restrict__ AO) {
    __shared__ __align__(16) short Ksh[2][128 * 64];   // per-group K tile; P overlay
    __shared__ __align__(16) short Vsh[2][64 * 128];   // per-group V^T tile

    const int t = threadIdx.x;
    const int g = t >> 8;            // wave-group 0/1
    const int tg = t & 255;          // thread-in-group
    const int w = (t >> 6) & 3;      // wave-in-group
    const int lane = t & 63, quad = lane >> 4, l16 = lane & 15;
    const int qb = blockIdx.x * 64;
    const int h = blockIdx.y, b = blockIdx.z;
    const int bh = b * NH + h;
    const int vl = vlen[b];
    const int nt = (vl + 127) >> 7;
    const int nrounds = (nt + 1) >> 1;

    const float SC = 0.180336879f;                   // 0.125 * log2(e)

    const short* qrow = &Qh[(bh * S_ + qb + w * 16 + l16) * DH];
    short8 qa0 = *(const short8*)&qrow[quad * 8];
    short8 qa1 = *(const short8*)&qrow[32 + quad * 8];

    short* Kc = Ksh[g];
    short* Vc = Vsh[g];
    short* Psh = Kc + (w << 11);                     // wave-local P region

    float m_run = -1e30f, l_run = 0.f;
    floatx4 Oacc[4];
    floatx4 zero = {0.f, 0.f, 0.f, 0.f};
#pragma unroll
    for (int dt = 0; dt < 4; dt++) Oacc[dt] = zero;

    for (int i = 0; i < nrounds; i++) {
        const int kt = 2 * i + g;
        const bool act = kt < nt;
        const int base = kt << 7;
        const bool bnd = (base + 128) > vl;

        __syncthreads();                             // #1: prev round PV/P done
        if (act) {
            const short* Kg = &Kh[(bh * S_ + base) * DH];
#pragma unroll
            for (int it = 0; it < 4; it++) {
                int idx = it * 256 + tg;
                int row = idx >> 3, c = idx & 7;
                *(short8*)&Kc[row * 64 + (((c ^ (row & 7))) << 3)] =
                    *(const short8*)&Kg[row * DH + (c << 3)];
            }
            const short* Vg = &VT[bh * DH * S_ + base];
#pragma unroll
            for (int it = 0; it < 4; it++) {
                int idx = it * 256 + tg;
                int d = idx >> 4, c = idx & 15;
                *(short8*)&Vc[d * 128 + (((c ^ (d & 7))) << 3)] =
                    *(const short8*)&Vg[d * S_ + (c << 3)];
            }
        }
        __syncthreads();                             // #2: staging visible

        floatx4 sc[8];
        if (act) {
            // S^T: rows = key, col = q (l16)
#pragma unroll
            for (int n = 0; n < 8; n++) {
                int kro = n * 16 + l16;
                const short* kr = &Kc[kro * 64];
                short8 kb0 = *(const short8*)&kr[((quad ^ (kro & 7)) << 3)];
                short8 kb1 = *(const short8*)&kr[(((4 + quad) ^ (kro & 7)) << 3)];
                floatx4 s = zero;
                s = mfma_s(kb0, qa0, s);
                s = mfma_s(kb1, qa1, s);
                sc[n] = s;
            }
        }
        __syncthreads();                             // #3: K reads done (P overlay)

        if (act) {
            // mask in RAW domain (SC > 0, so max commutes with scaling)
            if (bnd) {
#pragma unroll
                for (int n = 0; n < 8; n++)
#pragma unroll
                    for (int r = 0; r < 4; r++) {
                        int key = base + n * 16 + quad * 4 + r;
                        if (key >= vl) sc[n][r] = -1e30f;
                    }
            }

            // softmax (exp2 domain), per-lane q-column + 2 shuffles
            float mx = vmax4(sc[0]);
#pragma unroll
            for (int n = 1; n < 8; n++) mx = fmaxf(mx, vmax4(sc[n]));
            mx = fmaxf(mx, __shfl_xor(mx, 16));
            mx = fmaxf(mx, __shfl_xor(mx, 32));
            const float mxs = mx * SC;
            const bool norescale = __all(mxs <= m_run);
            const float mnew = norescale ? m_run : fmaxf(m_run, mxs);
            const float alpha = norescale ? 1.0f : __builtin_amdgcn_exp2f(m_run - mnew);
            m_run = mnew;
            float rs = 0.f;
#pragma unroll
            for (int n = 0; n < 8; n++)
#pragma unroll
                for (int r = 0; r < 4; r++) {
                    float p = __builtin_amdgcn_exp2f(fmaf(sc[n][r], SC, -mnew));
                    sc[n][r] = p;
                    rs += p;
                }
            rs += __shfl_xor(rs, 16);
            rs += __shfl_xor(rs, 32);
            l_run = l_run * alpha + rs;
            if (!norescale) {
#pragma unroll
                for (int dt = 0; dt < 4; dt++)
#pragma unroll
                    for (int r = 0; r < 4; r++) Oacc[dt][r] *= alpha;
            }

            // P^T store: 4 register-rows = 4 consecutive keys -> b64 writes
#pragma unroll
            for (int n = 0; n < 8; n++) {
                unsigned lo = pack2(sc[n][0], sc[n][1]);
                unsigned hi = pack2(sc[n][2], sc[n][3]);
                int c = (n << 1) + (quad >> 1);
                int idx = (l16 << 7) + ((c ^ (l16 & 7)) << 3) + ((quad & 1) << 2);
                uint2v pv; pv[0] = lo; pv[1] = hi;
                *(uint2v*)&Psh[idx] = pv;
            }
            // P is wave-local: no block barrier; pin write->read order.
            asm volatile("s_waitcnt lgkmcnt(0)" ::: "memory");
            __builtin_amdgcn_sched_barrier(0);

            // O^T += V^T * P^T
#pragma unroll
            for (int kk = 0; kk < 4; kk++) {
                int pc = (kk << 2) + quad;
                short8 pf = *(const short8*)&Psh[(l16 << 7) + ((pc ^ (l16 & 7)) << 3)];
#pragma unroll
                for (int dt = 0; dt < 4; dt++) {
                    int vrow = dt * 16 + l16;
                    short8 vf = *(const short8*)&Vc[vrow * 128 + ((pc ^ (vrow & 7)) << 3)];
                    Oacc[dt] = mfma_s(vf, pf, Oacc[dt]);
                }
            }
        }
    }

    // -------- in-block merge of the two groups' partials --------
    __syncthreads();                                 // loop done; LDS reusable
    float* Of = (float*)Ksh;                         // 256 thr x 16 f32 = 16 KB
    float* ml = (float*)Vsh;                         // 256 thr x 2 f32
    if (g == 1) {
#pragma unroll
        for (int dt = 0; dt < 4; dt++) *(floatx4*)&Of[tg * 16 + dt * 4] = Oacc[dt];
        ml[tg * 2] = m_run;
        ml[tg * 2 + 1] = l_run;
    }
    __syncthreads();
    if (g == 0) {
        float m1 = ml[tg * 2], l1 = ml[tg * 2 + 1];
        float mstar = fmaxf(m_run, m1);
        float s0 = __builtin_amdgcn_exp2f(m_run - mstar);
        float s1 = __builtin_amdgcn_exp2f(m1 - mstar);
        float inv = 1.0f / (l_run * s0 + l1 * s1);
        float a0 = s0 * inv, a1 = s1 * inv;
        int q = qb + w * 16 + l16;
        short* dst = &AO[(b * S_ + q) * HIDN + h * DH];
#pragma unroll
        for (int dt = 0; dt < 4; dt++) {
            floatx4 o1 = *(const floatx4*)&Of[tg * 16 + dt * 4];
            float v0 = Oacc[dt][0] * a0 + o1[0] * a1;
            float v1 = Oacc[dt][1] * a0 + o1[1] * a1;
            float v2 = Oacc[dt][2] * a0 + o1[2] * a1;
            float v3 = Oacc[dt][3] * a0 + o1[3] * a1;
            uint2v v;
            v[0] = pack2(v0, v1);
            v[1] = pack2(v2, v3);
            *(uint2v*)&dst[dt * 16 + quad * 4] = v;
        }
    }
}

extern "C" void kernel_launch(void* const* d_in, const int* in_sizes, int n_in,
                              void* d_out, int out_size, void* d_ws, size_t ws_size,
                              hipStream_t stream) {
    const float* q  = (const float*)d_in[0];
    const float* k  = (const float*)d_in[1];
    const float* v  = (const float*)d_in[2];
    const int*   vl = (const int*)d_in[3];
    const float* wq = (const float*)d_in[4];
    const float* wk = (const float*)d_in[5];
    const float* wv = (const float*)d_in[6];
    const float* wo = (const float*)d_in[7];
    float* out = (float*)d_out;

    const size_t HSZ = (size_t)B_ * NH * S_ * DH;  // 4.19M shorts
    short* Qh  = (short*)d_ws;
    short* Kh  = Qh + HSZ;
    short* VT  = Kh + HSZ;
    short* AO  = VT + HSZ;
    short* Wqkv = AO;   // 3*256K shorts in the AO region (dead until attn)

    dim3 blk(256);
    cvt_w<<<dim3(256, 3), blk, 0, stream>>>(wq, wk, wv, Wqkv);
    gemm_qkv<<<dim3(64, 4, 3), blk, 0, stream>>>(q, k, v, Wqkv, Qh, Kh, VT);
    attn_kernel<<<dim3(S_ / 64, NH, B_), dim3(512), 0, stream>>>(Qh, Kh, VT, vl, AO);
    gemm_out<<<dim3(64, 8), blk, 0, stream>>>(AO, wo, out);
}

// Round 4
// 186.594 us; speedup vs baseline: 1.0459x; 1.0459x over previous
//
#include <hip/hip_runtime.h>

#define B_ 4
#define S_ 2048
#define HIDN 512
#define NH 8
#define DH 64

typedef __attribute__((ext_vector_type(8))) short short8;
typedef __attribute__((ext_vector_type(4))) short short4v;
typedef __attribute__((ext_vector_type(8))) __bf16 bf16x8;
typedef __attribute__((ext_vector_type(4))) float floatx4;
typedef __attribute__((ext_vector_type(2))) unsigned uint2v;
typedef __attribute__((ext_vector_type(4))) unsigned uint4v;

__device__ inline short f2bf(float f) {            // RTNE
    union { float f; unsigned u; } x; x.f = f;
    unsigned r = x.u + 0x7fffu + ((x.u >> 16) & 1u);
    return (short)(r >> 16);
}

// pack two floats -> two bf16 (round-half-up) in one uint via v_perm
__device__ inline unsigned pack2(float a, float b) {
    unsigned ua = __builtin_bit_cast(unsigned, a) + 0x8000u;
    unsigned ub = __builtin_bit_cast(unsigned, b) + 0x8000u;
    return __builtin_amdgcn_perm(ub, ua, 0x07060302);  // shorts [a, b]
}

// 8 fp32 -> 8 bf16 (12 VALU)
__device__ inline short8 cvt8(const float* __restrict__ p) {
    floatx4 f0 = *(const floatx4*)p;
    floatx4 f1 = *(const floatx4*)(p + 4);
    uint4v u;
    u[0] = pack2(f0[0], f0[1]); u[1] = pack2(f0[2], f0[3]);
    u[2] = pack2(f1[0], f1[1]); u[3] = pack2(f1[2], f1[3]);
    return __builtin_bit_cast(short8, u);
}

__device__ inline floatx4 mfma_s(short8 a, short8 b, floatx4 c) {
    return __builtin_amdgcn_mfma_f32_16x16x32_bf16(
        __builtin_bit_cast(bf16x8, a), __builtin_bit_cast(bf16x8, b), c, 0, 0, 0);
}

__device__ inline float vmax4(floatx4 v) {
    return fmaxf(fmaxf(v[0], v[1]), fmaxf(v[2], v[3]));
}

// async global -> LDS, 16 B per lane; LDS dest = wave-uniform base + lane*16
__device__ inline void gl_lds(const short* g, short* l) {
    __builtin_amdgcn_global_load_lds(
        (const __attribute__((address_space(1))) void*)g,
        (__attribute__((address_space(3))) void*)l, 16, 0, 0);
}

// ---------------------------------------------------------------------------
// cvt_x: X (q,k,v activations) fp32 -> bf16. grid (2048,3) x 256, 8 elem/thr.
// ---------------------------------------------------------------------------
__global__ void cvt_x(const float* __restrict__ xq, const float* __restrict__ xk,
                      const float* __restrict__ xv, short* __restrict__ out) {
    const float* src = blockIdx.y == 0 ? xq : (blockIdx.y == 1 ? xk : xv);
    int i = (blockIdx.x * 256 + threadIdx.x) * 8;
    *(short8*)&out[(size_t)blockIdx.y * (B_ * S_ * HIDN) + i] = cvt8(&src[i]);
}

// ---------------------------------------------------------------------------
// cvt_w4: Wq,Wk,Wv,Wo fp32 -> bf16. grid (128,4) x 256, 8 elem/thr.
// ---------------------------------------------------------------------------
__global__ void cvt_w4(const float* __restrict__ wq, const float* __restrict__ wk,
                       const float* __restrict__ wv, const float* __restrict__ wo,
                       short* __restrict__ out) {
    const float* src = blockIdx.y == 0 ? wq :
                       (blockIdx.y == 1 ? wk : (blockIdx.y == 2 ? wv : wo));
    int i = (blockIdx.x * 256 + threadIdx.x) * 8;
    *(short8*)&out[blockIdx.y * (HIDN * HIDN) + i] = cvt8(&src[i]);
}

// ---------------------------------------------------------------------------
// gemm_qkv2: pure-bf16 QKV projection, m97-style global_load_lds staging.
// grid (64,4,3); z=0:Q, z=1:K (head layout), z=2:V^T. 128x128 tile, BK=64,
// linear LDS [128][64], 2-barrier K-loop, 8x async 16B direct-to-LDS loads.
// ---------------------------------------------------------------------------
__global__ __launch_bounds__(256) void gemm_qkv2(const short* __restrict__ Xb,
                                                 const short* __restrict__ wb,
                                                 short* __restrict__ Qh,
                                                 short* __restrict__ Kh,
                                                 short* __restrict__ VT) {
    const int z = blockIdx.z;
    const short* X = Xb + (size_t)z * (B_ * S_ * HIDN);
    const short* W = wb + z * (HIDN * HIDN);
    short* dstQK = z == 0 ? Qh : Kh;

    __shared__ __align__(16) short Als[128 * 64];
    __shared__ __align__(16) short Bls[128 * 64];

    const int t = threadIdx.x;
    const int w = t >> 6, lane = t & 63, quad = lane >> 4, l16 = lane & 15;
    const int wm = (w & 1) * 64, wn = (w >> 1) * 64;
    const int m0 = blockIdx.x * 128, n0 = blockIdx.y * 128;

    floatx4 acc[4][4];
    floatx4 zero = {0.f, 0.f, 0.f, 0.f};
#pragma unroll
    for (int i = 0; i < 4; i++)
#pragma unroll
        for (int j = 0; j < 4; j++) acc[i][j] = zero;

    const int srow = t >> 3;        // 0..31 (+32/iter)
    const int sc8 = (t & 7) * 8;    // 0..56
    const int ldsb = (t & ~63) * 8; // wave-uniform chunk base (shorts)

    for (int k0 = 0; k0 < HIDN; k0 += 64) {
        __syncthreads();            // prev compute's LDS reads done
#pragma unroll
        for (int it = 0; it < 4; it++)
            gl_lds(&X[(size_t)(m0 + srow + it * 32) * HIDN + k0 + sc8],
                   &Als[it * 2048 + ldsb]);
#pragma unroll
        for (int it = 0; it < 4; it++)
            gl_lds(&W[(n0 + srow + it * 32) * HIDN + k0 + sc8],
                   &Bls[it * 2048 + ldsb]);
        __syncthreads();            // implicit vmcnt(0): staging visible

#pragma unroll
        for (int ks = 0; ks < 2; ks++) {
            const int cq8 = (ks * 4 + quad) * 8;
            short8 a[4], b[4];
#pragma unroll
            for (int i = 0; i < 4; i++)
                a[i] = *(const short8*)&Als[(wm + i * 16 + l16) * 64 + cq8];
#pragma unroll
            for (int j = 0; j < 4; j++)
                b[j] = *(const short8*)&Bls[(wn + j * 16 + l16) * 64 + cq8];
#pragma unroll
            for (int i = 0; i < 4; i++)
#pragma unroll
                for (int j = 0; j < 4; j++)
                    acc[i][j] = mfma_s(a[i], b[j], acc[i][j]);
        }
    }

    if (z < 2) {   // head layout (B,NH,S,DH)
#pragma unroll
        for (int i = 0; i < 4; i++)
#pragma unroll
            for (int j = 0; j < 4; j++)
#pragma unroll
                for (int r = 0; r < 4; r++) {
                    int m = m0 + wm + i*16 + quad*4 + r;
                    int n = n0 + wn + j*16 + l16;
                    int bb = m >> 11, s = m & 2047, h = n >> 6, d = n & 63;
                    dstQK[((bb * NH + h) * S_ + s) * DH + d] = f2bf(acc[i][j][r]);
                }
    } else {       // V^T (B,NH,DH,S)
#pragma unroll
        for (int i = 0; i < 4; i++)
#pragma unroll
            for (int j = 0; j < 4; j++) {
                int s0 = m0 + wm + i*16 + quad*4;
                int n = n0 + wn + j*16 + l16;
                int bb = s0 >> 11, s = s0 & 2047, h = n >> 6, d = n & 63;
                uint2v v;
                v[0] = pack2(acc[i][j][0], acc[i][j][1]);
                v[1] = pack2(acc[i][j][2], acc[i][j][3]);
                *(uint2v*)&VT[((bb * NH + h) * DH + d) * S_ + s] = v;
            }
    }
}

// ---------------------------------------------------------------------------
// gemm_out2: pure-bf16 out projection, same m97-style structure, fp32 out.
// grid (64,4). 128x128 tile.
// ---------------------------------------------------------------------------
__global__ __launch_bounds__(256) void gemm_out2(const short* __restrict__ AO,
                                                 const short* __restrict__ WoB,
                                                 float* __restrict__ C) {
    __shared__ __align__(16) short Als[128 * 64];
    __shared__ __align__(16) short Bls[128 * 64];

    const int t = threadIdx.x;
    const int w = t >> 6, lane = t & 63, quad = lane >> 4, l16 = lane & 15;
    const int wm = (w & 1) * 64, wn = (w >> 1) * 64;
    const int m0 = blockIdx.x * 128, n0 = blockIdx.y * 128;

    floatx4 acc[4][4];
    floatx4 zero = {0.f, 0.f, 0.f, 0.f};
#pragma unroll
    for (int i = 0; i < 4; i++)
#pragma unroll
        for (int j = 0; j < 4; j++) acc[i][j] = zero;

    const int srow = t >> 3;
    const int sc8 = (t & 7) * 8;
    const int ldsb = (t & ~63) * 8;

    for (int k0 = 0; k0 < HIDN; k0 += 64) {
        __syncthreads();
#pragma unroll
        for (int it = 0; it < 4; it++)
            gl_lds(&AO[(size_t)(m0 + srow + it * 32) * HIDN + k0 + sc8],
                   &Als[it * 2048 + ldsb]);
#pragma unroll
        for (int it = 0; it < 4; it++)
            gl_lds(&WoB[(n0 + srow + it * 32) * HIDN + k0 + sc8],
                   &Bls[it * 2048 + ldsb]);
        __syncthreads();

#pragma unroll
        for (int ks = 0; ks < 2; ks++) {
            const int cq8 = (ks * 4 + quad) * 8;
            short8 a[4], b[4];
#pragma unroll
            for (int i = 0; i < 4; i++)
                a[i] = *(const short8*)&Als[(wm + i * 16 + l16) * 64 + cq8];
#pragma unroll
            for (int j = 0; j < 4; j++)
                b[j] = *(const short8*)&Bls[(wn + j * 16 + l16) * 64 + cq8];
#pragma unroll
            for (int i = 0; i < 4; i++)
#pragma unroll
                for (int j = 0; j < 4; j++)
                    acc[i][j] = mfma_s(a[i], b[j], acc[i][j]);
        }
    }

#pragma unroll
    for (int i = 0; i < 4; i++)
#pragma unroll
        for (int j = 0; j < 4; j++)
#pragma unroll
            for (int r = 0; r < 4; r++) {
                int m = m0 + wm + i*16 + quad*4 + r;
                int n = n0 + wn + j*16 + l16;
                C[m * HIDN + n] = acc[i][j][r];
            }
}

// ---------------------------------------------------------------------------
// ===== LEGACY PATH (round-0 verbatim) — used only if ws_size too small =====
// ---------------------------------------------------------------------------
__global__ void cvt_w3(const float* __restrict__ wq, const float* __restrict__ wk,
                       const float* __restrict__ wv, short* __restrict__ out) {
    const float* src = blockIdx.y == 0 ? wq : (blockIdx.y == 1 ? wk : wv);
    int i = (blockIdx.x * 256 + threadIdx.x) * 4;
    floatx4 f = *(const floatx4*)&src[i];
    short4v v; v[0]=f2bf(f[0]); v[1]=f2bf(f[1]); v[2]=f2bf(f[2]); v[3]=f2bf(f[3]);
    *(short4v*)&out[blockIdx.y * (HIDN * HIDN) + i] = v;
}

__global__ __launch_bounds__(256) void gemm_qkv(const float* __restrict__ xq,
                                                const float* __restrict__ xk,
                                                const float* __restrict__ xv,
                                                const short* __restrict__ wb,
                                                short* __restrict__ Qh,
                                                short* __restrict__ Kh,
                                                short* __restrict__ VT) {
    const int z = blockIdx.z;
    const float* X = z == 0 ? xq : (z == 1 ? xk : xv);
    const short* W = wb + z * (HIDN * HIDN);
    short* dstQK = z == 0 ? Qh : Kh;

    __shared__ __align__(16) short Als[128][72];
    __shared__ __align__(16) short Bls[128][72];

    const int t = threadIdx.x;
    const int w = t >> 6, lane = t & 63, quad = lane >> 4, l16 = lane & 15;
    const int wm = (w & 1) * 64, wn = (w >> 1) * 64;
    const int m0 = blockIdx.x * 128, n0 = blockIdx.y * 128;

    floatx4 acc[4][4];
    floatx4 zero = {0.f, 0.f, 0.f, 0.f};
#pragma unroll
    for (int i = 0; i < 4; i++)
#pragma unroll
        for (int j = 0; j < 4; j++) acc[i][j] = zero;

    const int row0 = t >> 3;
    const int c8 = (t & 7) * 8;

    for (int k0 = 0; k0 < HIDN; k0 += 64) {
        __syncthreads();
#pragma unroll
        for (int rr = 0; rr < 4; rr++)
            *(short8*)&Als[row0 + rr*32][c8] =
                cvt8(&X[(m0 + row0 + rr*32) * HIDN + k0 + c8]);
#pragma unroll
        for (int rr = 0; rr < 4; rr++)
            *(short8*)&Bls[row0 + rr*32][c8] =
                *(const short8*)&W[(n0 + row0 + rr*32) * HIDN + k0 + c8];
        __syncthreads();

#pragma unroll
        for (int ks = 0; ks < 2; ks++) {
            const int cq8 = (ks * 4 + quad) * 8;
            short8 a[4], b[4];
#pragma unroll
            for (int i = 0; i < 4; i++)
                a[i] = *(const short8*)&Als[wm + i*16 + l16][cq8];
#pragma unroll
            for (int j = 0; j < 4; j++)
                b[j] = *(const short8*)&Bls[wn + j*16 + l16][cq8];
#pragma unroll
            for (int i = 0; i < 4; i++)
#pragma unroll
                for (int j = 0; j < 4; j++)
                    acc[i][j] = mfma_s(a[i], b[j], acc[i][j]);
        }
    }

    if (z < 2) {
#pragma unroll
        for (int i = 0; i < 4; i++)
#pragma unroll
            for (int j = 0; j < 4; j++)
#pragma unroll
                for (int r = 0; r < 4; r++) {
                    int m = m0 + wm + i*16 + quad*4 + r;
                    int n = n0 + wn + j*16 + l16;
                    int bb = m >> 11, s = m & 2047, h = n >> 6, d = n & 63;
                    dstQK[((bb * NH + h) * S_ + s) * DH + d] = f2bf(acc[i][j][r]);
                }
    } else {
#pragma unroll
        for (int i = 0; i < 4; i++)
#pragma unroll
            for (int j = 0; j < 4; j++) {
                int s0 = m0 + wm + i*16 + quad*4;
                int n = n0 + wn + j*16 + l16;
                int bb = s0 >> 11, s = s0 & 2047, h = n >> 6, d = n & 63;
                uint2v v;
                v[0] = pack2(acc[i][j][0], acc[i][j][1]);
                v[1] = pack2(acc[i][j][2], acc[i][j][3]);
                *(uint2v*)&VT[((bb * NH + h) * DH + d) * S_ + s] = v;
            }
    }
}

__global__ __launch_bounds__(256) void gemm_out(const short* __restrict__ AO,
                                                const float* __restrict__ Wo,
                                                float* __restrict__ C) {
    __shared__ __align__(16) short Als[128][72];
    __shared__ __align__(16) short Bls[64][72];

    const int t = threadIdx.x;
    const int w = t >> 6, lane = t & 63, quad = lane >> 4, l16 = lane & 15;
    const int wm = (w & 1) * 64, wn = (w >> 1) * 32;
    const int m0 = blockIdx.x * 128, n0 = blockIdx.y * 64;

    floatx4 acc[4][2];
    floatx4 zero = {0.f, 0.f, 0.f, 0.f};
#pragma unroll
    for (int i = 0; i < 4; i++)
#pragma unroll
        for (int j = 0; j < 2; j++) acc[i][j] = zero;

    const int row0 = t >> 3;
    const int c8 = (t & 7) * 8;

    for (int k0 = 0; k0 < HIDN; k0 += 64) {
        __syncthreads();
#pragma unroll
        for (int rr = 0; rr < 4; rr++)
            *(short8*)&Als[row0 + rr*32][c8] =
                *(const short8*)&AO[(m0 + row0 + rr*32) * HIDN + k0 + c8];
#pragma unroll
        for (int rr = 0; rr < 2; rr++)
            *(short8*)&Bls[row0 + rr*32][c8] =
                cvt8(&Wo[(n0 + row0 + rr*32) * HIDN + k0 + c8]);
        __syncthreads();

#pragma unroll
        for (int ks = 0; ks < 2; ks++) {
            const int cq8 = (ks * 4 + quad) * 8;
            short8 a[4], b[2];
#pragma unroll
            for (int i = 0; i < 4; i++)
                a[i] = *(const short8*)&Als[wm + i*16 + l16][cq8];
#pragma unroll
            for (int j = 0; j < 2; j++)
                b[j] = *(const short8*)&Bls[wn + j*16 + l16][cq8];
#pragma unroll
            for (int i = 0; i < 4; i++)
#pragma unroll
                for (int j = 0; j < 2; j++)
                    acc[i][j] = mfma_s(a[i], b[j], acc[i][j]);
        }
    }

#pragma unroll
    for (int i = 0; i < 4; i++)
#pragma unroll
        for (int j = 0; j < 2; j++)
#pragma unroll
            for (int r = 0; r < 4; r++) {
                int m = m0 + wm + i*16 + quad*4 + r;
                int n = n0 + wn + j*16 + l16;
                C[m * HIDN + n] = acc[i][j][r];
            }
}

// ---------------------------------------------------------------------------
// Flash attention — round-0 champion VERBATIM (50.2 us proven).
// Transposed orientation: S^T = K·Q^T; O^T = V^T·P^T. XOR-swizzled LDS;
// P overlays K region (32 KB -> 4 blk/CU LDS-wise).
// ---------------------------------------------------------------------------
__global__ __launch_bounds__(256, 4) void attn_kernel(const short* __restrict__ Qh,
                                                      const short* __restrict__ Kh,
                                                      const short* __restrict__ VT,
                                                      const int* __restrict__ vlen,
                                                      short* __restrict__ AO) {
    __shared__ __align__(16) short Ksh[128 * 64];   // K tile; overlaid by P
    __shared__ __align__(16) short Vsh[64 * 128];   // V^T tile
    short* Psh = Ksh;                                // wave w region: w*2048 shorts

    const int t = threadIdx.x, w = t >> 6, lane = t & 63;
    const int quad = lane >> 4, l16 = lane & 15;
    const int qb = blockIdx.x * 64;
    const int h = blockIdx.y, b = blockIdx.z;
    const int bh = b * NH + h;
    const int vl = vlen[b];
    const int nfull = vl >> 7, rem = vl & 127;
    const int nt = nfull + (rem ? 1 : 0);

    const float SC = 0.180336879f;                   // 0.125 * log2(e)

    const short* qrow = &Qh[(bh * S_ + qb + w * 16 + l16) * DH];
    short8 qa0 = *(const short8*)&qrow[quad * 8];
    short8 qa1 = *(const short8*)&qrow[32 + quad * 8];

    float m_run = -1e30f, l_run = 0.f;
    floatx4 Oacc[4];
    floatx4 zero = {0.f, 0.f, 0.f, 0.f};
#pragma unroll
    for (int dt = 0; dt < 4; dt++) Oacc[dt] = zero;

    for (int kt = 0; kt < nt; kt++) {
        const int base = kt << 7;
        const bool bnd = (base + 128) > vl;
        __syncthreads();                             // prev PV reads done
        {
            const short* Kg = &Kh[(bh * S_ + base) * DH];
#pragma unroll
            for (int it = 0; it < 4; it++) {
                int idx = it * 256 + t;
                int row = idx >> 3, c = idx & 7;
                *(short8*)&Ksh[row * 64 + (((c ^ (row & 7))) << 3)] =
                    *(const short8*)&Kg[row * DH + (c << 3)];
            }
            const short* Vg = &VT[bh * DH * S_ + base];
#pragma unroll
            for (int it = 0; it < 4; it++) {
                int idx = it * 256 + t;
                int d = idx >> 4, c = idx & 15;
                *(short8*)&Vsh[d * 128 + (((c ^ (d & 7))) << 3)] =
                    *(const short8*)&Vg[d * S_ + (c << 3)];
            }
        }
        __syncthreads();                             // staging visible

        // S^T: rows = key, col = q (l16)
        floatx4 sc[8];
#pragma unroll
        for (int n = 0; n < 8; n++) {
            int krow = n * 16 + l16;
            const short* kr = &Ksh[krow * 64];
            short8 kb0 = *(const short8*)&kr[((quad ^ (krow & 7)) << 3)];
            short8 kb1 = *(const short8*)&kr[(((4 + quad) ^ (krow & 7)) << 3)];
            floatx4 s = zero;
            s = mfma_s(kb0, qa0, s);
            s = mfma_s(kb1, qa1, s);
            sc[n] = s;
        }
        __syncthreads();                             // all Ksh reads done (P overlay)

        if (!bnd) {
#pragma unroll
            for (int n = 0; n < 8; n++)
#pragma unroll
                for (int r = 0; r < 4; r++) sc[n][r] *= SC;
        } else {
#pragma unroll
            for (int n = 0; n < 8; n++)
#pragma unroll
                for (int r = 0; r < 4; r++) {
                    int key = base + n * 16 + quad * 4 + r;
                    sc[n][r] = (key < vl) ? sc[n][r] * SC : -1e30f;
                }
        }

        // softmax (exp2 domain), per-lane q-column + 2 shuffles
        float mx = vmax4(sc[0]);
#pragma unroll
        for (int n = 1; n < 8; n++) mx = fmaxf(mx, vmax4(sc[n]));
        mx = fmaxf(mx, __shfl_xor(mx, 16));
        mx = fmaxf(mx, __shfl_xor(mx, 32));
        float mnew = fmaxf(m_run, mx);
        float alpha = __builtin_amdgcn_exp2f(m_run - mnew);
        m_run = mnew;
        float rs = 0.f;
#pragma unroll
        for (int n = 0; n < 8; n++)
#pragma unroll
            for (int r = 0; r < 4; r++) {
                float p = __builtin_amdgcn_exp2f(sc[n][r] - mnew);
                sc[n][r] = p;
                rs += p;
            }
        rs += __shfl_xor(rs, 16);
        rs += __shfl_xor(rs, 32);
        l_run = l_run * alpha + rs;
#pragma unroll
        for (int dt = 0; dt < 4; dt++)
#pragma unroll
            for (int r = 0; r < 4; r++) Oacc[dt][r] *= alpha;   // alpha lane-uniform

        // P^T store: 4 register-rows = 4 consecutive keys -> b64 writes
#pragma unroll
        for (int n = 0; n < 8; n++) {
            unsigned lo = pack2(sc[n][0], sc[n][1]);
            unsigned hi = pack2(sc[n][2], sc[n][3]);
            int c = (n << 1) + (quad >> 1);
            int idx = (w << 11) + (l16 << 7) + ((c ^ (l16 & 7)) << 3) + ((quad & 1) << 2);
            uint2v pv; pv[0] = lo; pv[1] = hi;
            *(uint2v*)&Psh[idx] = pv;
        }
        __syncthreads();                             // P visible + ordered

        // O^T += V^T * P^T
#pragma unroll
        for (int kk = 0; kk < 4; kk++) {
            int pc = (kk << 2) + quad;
            short8 pf = *(const short8*)&Psh[(w << 11) + (l16 << 7) + ((pc ^ (l16 & 7)) << 3)];
#pragma unroll
            for (int dt = 0; dt < 4; dt++) {
                int vrow = dt * 16 + l16;
                short8 vf = *(const short8*)&Vsh[vrow * 128 + ((pc ^ (vrow & 7)) << 3)];
                Oacc[dt] = mfma_s(vf, pf, Oacc[dt]);
            }
        }
    }

    // epilogue
    float inv = 1.0f / l_run;
    int q = qb + w * 16 + l16;
    short* dst = &AO[(b * S_ + q) * HIDN + h * DH];
#pragma unroll
    for (int dt = 0; dt < 4; dt++) {
        uint2v v;
        v[0] = pack2(Oacc[dt][0] * inv, Oacc[dt][1] * inv);
        v[1] = pack2(Oacc[dt][2] * inv, Oacc[dt][3] * inv);
        *(uint2v*)&dst[dt * 16 + quad * 4] = v;
    }
}

extern "C" void kernel_launch(void* const* d_in, const int* in_sizes, int n_in,
                              void* d_out, int out_size, void* d_ws, size_t ws_size,
                              hipStream_t stream) {
    const float* q  = (const float*)d_in[0];
    const float* k  = (const float*)d_in[1];
    const float* v  = (const float*)d_in[2];
    const int*   vl = (const int*)d_in[3];
    const float* wq = (const float*)d_in[4];
    const float* wk = (const float*)d_in[5];
    const float* wv = (const float*)d_in[6];
    const float* wo = (const float*)d_in[7];
    float* out = (float*)d_out;

    const size_t HSZ = (size_t)B_ * NH * S_ * DH;  // 4.19M shorts per tensor
    const size_t WSZ = (size_t)HIDN * HIDN;        // 262K shorts per weight

    short* Qh  = (short*)d_ws;
    short* Kh  = Qh + HSZ;
    short* VT  = Kh + HSZ;
    short* AO  = VT + HSZ;

    dim3 blk(256);
    const size_t need = (4 * HSZ + 3 * HSZ + 4 * WSZ) * sizeof(short);

    if (ws_size >= need) {
        // ---- new path: pre-converted bf16 X + W, async-staged GEMMs ----
        short* Xb = AO + HSZ;          // 3*HSZ
        short* Wb = Xb + 3 * HSZ;      // 4*WSZ
        cvt_x<<<dim3(2048, 3), blk, 0, stream>>>(q, k, v, Xb);
        cvt_w4<<<dim3(128, 4), blk, 0, stream>>>(wq, wk, wv, wo, Wb);
        gemm_qkv2<<<dim3(64, 4, 3), blk, 0, stream>>>(Xb, Wb, Qh, Kh, VT);
        attn_kernel<<<dim3(S_ / 64, NH, B_), blk, 0, stream>>>(Qh, Kh, VT, vl, AO);
        gemm_out2<<<dim3(64, 4), blk, 0, stream>>>(AO, Wb + 3 * WSZ, out);
    } else {
        // ---- legacy round-0 path ----
        short* Wqkv = AO;   // 3*WSZ shorts in the AO region (dead until attn)
        cvt_w3<<<dim3(256, 3), blk, 0, stream>>>(wq, wk, wv, Wqkv);
        gemm_qkv<<<dim3(64, 4, 3), blk, 0, stream>>>(q, k, v, Wqkv, Qh, Kh, VT);
        attn_kernel<<<dim3(S_ / 64, NH, B_), blk, 0, stream>>>(Qh, Kh, VT, vl, AO);
        gemm_out<<<dim3(64, 8), blk, 0, stream>>>(AO, wo, out);
    }
}

// Round 5
// 174.081 us; speedup vs baseline: 1.1211x; 1.0719x over previous
//
#include <hip/hip_runtime.h>

#define B_ 4
#define S_ 2048
#define HIDN 512
#define NH 8
#define DH 64

typedef __attribute__((ext_vector_type(8))) short short8;
typedef __attribute__((ext_vector_type(4))) short short4v;
typedef __attribute__((ext_vector_type(8))) __bf16 bf16x8;
typedef __attribute__((ext_vector_type(4))) float floatx4;
typedef __attribute__((ext_vector_type(2))) unsigned uint2v;
typedef __attribute__((ext_vector_type(4))) unsigned uint4v;

__device__ inline short f2bf(float f) {            // RTNE
    union { float f; unsigned u; } x; x.f = f;
    unsigned r = x.u + 0x7fffu + ((x.u >> 16) & 1u);
    return (short)(r >> 16);
}

// pack two floats -> two bf16 (round-half-up) in one uint via v_perm
__device__ inline unsigned pack2(float a, float b) {
    unsigned ua = __builtin_bit_cast(unsigned, a) + 0x8000u;
    unsigned ub = __builtin_bit_cast(unsigned, b) + 0x8000u;
    return __builtin_amdgcn_perm(ub, ua, 0x07060302);  // shorts [a, b]
}

// 8 fp32 -> 8 bf16 (12 VALU)
__device__ inline short8 cvt8(const float* __restrict__ p) {
    floatx4 f0 = *(const floatx4*)p;
    floatx4 f1 = *(const floatx4*)(p + 4);
    uint4v u;
    u[0] = pack2(f0[0], f0[1]); u[1] = pack2(f0[2], f0[3]);
    u[2] = pack2(f1[0], f1[1]); u[3] = pack2(f1[2], f1[3]);
    return __builtin_bit_cast(short8, u);
}

__device__ inline floatx4 mfma_s(short8 a, short8 b, floatx4 c) {
    return __builtin_amdgcn_mfma_f32_16x16x32_bf16(
        __builtin_bit_cast(bf16x8, a), __builtin_bit_cast(bf16x8, b), c, 0, 0, 0);
}

__device__ inline float vmax4(floatx4 v) {
    return fmaxf(fmaxf(v[0], v[1]), fmaxf(v[2], v[3]));
}

// ---------------------------------------------------------------------------
// Pre-convert Wq,Wk,Wv (fp32 -> bf16). grid (256,3) x 256 thr, 4 elem/thr.
// ---------------------------------------------------------------------------
__global__ void cvt_w(const float* __restrict__ wq, const float* __restrict__ wk,
                      const float* __restrict__ wv, short* __restrict__ out) {
    const float* src = blockIdx.y == 0 ? wq : (blockIdx.y == 1 ? wk : wv);
    int i = (blockIdx.x * 256 + threadIdx.x) * 4;
    floatx4 f = *(const floatx4*)&src[i];
    short4v v; v[0]=f2bf(f[0]); v[1]=f2bf(f[1]); v[2]=f2bf(f[2]); v[3]=f2bf(f[3]);
    *(short4v*)&out[blockIdx.y * (HIDN * HIDN) + i] = v;
}

// ---------------------------------------------------------------------------
// Fused QKV projection (round-0 verbatim). grid (64,4,3); z=0:Q, z=1:K,
// z=2:V^T. r4 2D-padded idiom, BK=64. X fp32 cvt in staging; W bf16.
// ---------------------------------------------------------------------------
__global__ __launch_bounds__(256) void gemm_qkv(const float* __restrict__ xq,
                                                const float* __restrict__ xk,
                                                const float* __restrict__ xv,
                                                const short* __restrict__ wb,
                                                short* __restrict__ Qh,
                                                short* __restrict__ Kh,
                                                short* __restrict__ VT) {
    const int z = blockIdx.z;
    const float* X = z == 0 ? xq : (z == 1 ? xk : xv);
    const short* W = wb + z * (HIDN * HIDN);
    short* dstQK = z == 0 ? Qh : Kh;

    __shared__ __align__(16) short Als[128][72];   // 64 cols + pad to 72
    __shared__ __align__(16) short Bls[128][72];

    const int t = threadIdx.x;
    const int w = t >> 6, lane = t & 63, quad = lane >> 4, l16 = lane & 15;
    const int wm = (w & 1) * 64, wn = (w >> 1) * 64;
    const int m0 = blockIdx.x * 128, n0 = blockIdx.y * 128;

    floatx4 acc[4][4];
    floatx4 zero = {0.f, 0.f, 0.f, 0.f};
#pragma unroll
    for (int i = 0; i < 4; i++)
#pragma unroll
        for (int j = 0; j < 4; j++) acc[i][j] = zero;

    const int row0 = t >> 3;        // 0..31
    const int c8 = (t & 7) * 8;     // 0..56

    for (int k0 = 0; k0 < HIDN; k0 += 64) {
        __syncthreads();
#pragma unroll
        for (int rr = 0; rr < 4; rr++)
            *(short8*)&Als[row0 + rr*32][c8] =
                cvt8(&X[(m0 + row0 + rr*32) * HIDN + k0 + c8]);
#pragma unroll
        for (int rr = 0; rr < 4; rr++)
            *(short8*)&Bls[row0 + rr*32][c8] =
                *(const short8*)&W[(n0 + row0 + rr*32) * HIDN + k0 + c8];
        __syncthreads();

#pragma unroll
        for (int ks = 0; ks < 2; ks++) {
            const int cq8 = (ks * 4 + quad) * 8;
            short8 a[4], b[4];
#pragma unroll
            for (int i = 0; i < 4; i++)
                a[i] = *(const short8*)&Als[wm + i*16 + l16][cq8];
#pragma unroll
            for (int j = 0; j < 4; j++)
                b[j] = *(const short8*)&Bls[wn + j*16 + l16][cq8];
#pragma unroll
            for (int i = 0; i < 4; i++)
#pragma unroll
                for (int j = 0; j < 4; j++)
                    acc[i][j] = mfma_s(a[i], b[j], acc[i][j]);
        }
    }

    if (z < 2) {   // head layout (B,NH,S,DH)
#pragma unroll
        for (int i = 0; i < 4; i++)
#pragma unroll
            for (int j = 0; j < 4; j++)
#pragma unroll
                for (int r = 0; r < 4; r++) {
                    int m = m0 + wm + i*16 + quad*4 + r;
                    int n = n0 + wn + j*16 + l16;
                    int bb = m >> 11, s = m & 2047, h = n >> 6, d = n & 63;
                    dstQK[((bb * NH + h) * S_ + s) * DH + d] = f2bf(acc[i][j][r]);
                }
    } else {       // V^T (B,NH,DH,S)
#pragma unroll
        for (int i = 0; i < 4; i++)
#pragma unroll
            for (int j = 0; j < 4; j++) {
                int s0 = m0 + wm + i*16 + quad*4;
                int n = n0 + wn + j*16 + l16;
                int bb = s0 >> 11, s = s0 & 2047, h = n >> 6, d = n & 63;
                uint2v v;
                v[0] = pack2(acc[i][j][0], acc[i][j][1]);
                v[1] = pack2(acc[i][j][2], acc[i][j][3]);
                *(uint2v*)&VT[((bb * NH + h) * DH + d) * S_ + s] = v;
            }
    }
}

// ---------------------------------------------------------------------------
// Out projection (round-0 verbatim). 128x64 tile, grid(64,8), BK=64 padded.
// ---------------------------------------------------------------------------
__global__ __launch_bounds__(256) void gemm_out(const short* __restrict__ AO,
                                                const float* __restrict__ Wo,
                                                float* __restrict__ C) {
    __shared__ __align__(16) short Als[128][72];
    __shared__ __align__(16) short Bls[64][72];

    const int t = threadIdx.x;
    const int w = t >> 6, lane = t & 63, quad = lane >> 4, l16 = lane & 15;
    const int wm = (w & 1) * 64, wn = (w >> 1) * 32;
    const int m0 = blockIdx.x * 128, n0 = blockIdx.y * 64;

    floatx4 acc[4][2];
    floatx4 zero = {0.f, 0.f, 0.f, 0.f};
#pragma unroll
    for (int i = 0; i < 4; i++)
#pragma unroll
        for (int j = 0; j < 2; j++) acc[i][j] = zero;

    const int row0 = t >> 3;        // 0..31
    const int c8 = (t & 7) * 8;     // 0..56

    for (int k0 = 0; k0 < HIDN; k0 += 64) {
        __syncthreads();
#pragma unroll
        for (int rr = 0; rr < 4; rr++)
            *(short8*)&Als[row0 + rr*32][c8] =
                *(const short8*)&AO[(m0 + row0 + rr*32) * HIDN + k0 + c8];
#pragma unroll
        for (int rr = 0; rr < 2; rr++)
            *(short8*)&Bls[row0 + rr*32][c8] =
                cvt8(&Wo[(n0 + row0 + rr*32) * HIDN + k0 + c8]);
        __syncthreads();

#pragma unroll
        for (int ks = 0; ks < 2; ks++) {
            const int cq8 = (ks * 4 + quad) * 8;
            short8 a[4], b[2];
#pragma unroll
            for (int i = 0; i < 4; i++)
                a[i] = *(const short8*)&Als[wm + i*16 + l16][cq8];
#pragma unroll
            for (int j = 0; j < 2; j++)
                b[j] = *(const short8*)&Bls[wn + j*16 + l16][cq8];
#pragma unroll
            for (int i = 0; i < 4; i++)
#pragma unroll
                for (int j = 0; j < 2; j++)
                    acc[i][j] = mfma_s(a[i], b[j], acc[i][j]);
        }
    }

#pragma unroll
    for (int i = 0; i < 4; i++)
#pragma unroll
        for (int j = 0; j < 2; j++)
#pragma unroll
            for (int r = 0; r < 4; r++) {
                int m = m0 + wm + i*16 + quad*4 + r;
                int n = n0 + wn + j*16 + l16;
                C[m * HIDN + n] = acc[i][j][r];
            }
}

// ---------------------------------------------------------------------------
// Flash attention — round-0 body VERBATIM + h-clustered XCD swizzle (T1).
// Grid = flat 1024. Bijective remap wgid = (orig%8)*128 + orig/8 makes
// orig%8 == h: XCD k owns head k for ALL batches -> its K/V working set
// (~1.2 MB) is L2-resident, killing the measured ~4x K/V re-fetch (41 MB).
// Load balance preserved: each CU still gets one block per batch b (same-h,
// all-b), so per-CU work stays Sum_b vl_b, identical to the unswizzled map.
// ---------------------------------------------------------------------------
__global__ __launch_bounds__(256, 4) void attn_kernel(const short* __restrict__ Qh,
                                                      const short* __restrict__ Kh,
                                                      const short* __restrict__ VT,
                                                      const int* __restrict__ vlen,
                                                      short* __restrict__ AO) {
    __shared__ __align__(16) short Ksh[128 * 64];   // K tile; overlaid by P
    __shared__ __align__(16) short Vsh[64 * 128];   // V^T tile
    short* Psh = Ksh;                                // wave w region: w*2048 shorts

    const int t = threadIdx.x, w = t >> 6, lane = t & 63;
    const int quad = lane >> 4, l16 = lane & 15;

    // XCD swizzle: orig%8 -> XCD; make that the head index.
    const int orig = blockIdx.x;                     // 0..1023
    const int wgid = ((orig & 7) << 7) + (orig >> 3);
    const int h = wgid >> 7;                         // 0..7  (== orig%8 == XCD)
    const int rem = wgid & 127;
    const int b = rem >> 5;                          // 0..3
    const int qb = (rem & 31) * 64;                  // q-tile
    const int bh = b * NH + h;
    const int vl = vlen[b];
    const int nfull = vl >> 7, rem128 = vl & 127;
    const int nt = nfull + (rem128 ? 1 : 0);

    const float SC = 0.180336879f;                   // 0.125 * log2(e)

    const short* qrow = &Qh[(bh * S_ + qb + w * 16 + l16) * DH];
    short8 qa0 = *(const short8*)&qrow[quad * 8];
    short8 qa1 = *(const short8*)&qrow[32 + quad * 8];

    float m_run = -1e30f, l_run = 0.f;
    floatx4 Oacc[4];
    floatx4 zero = {0.f, 0.f, 0.f, 0.f};
#pragma unroll
    for (int dt = 0; dt < 4; dt++) Oacc[dt] = zero;

    for (int kt = 0; kt < nt; kt++) {
        const int base = kt << 7;
        const bool bnd = (base + 128) > vl;
        __syncthreads();                             // prev PV reads done
        {
            const short* Kg = &Kh[(bh * S_ + base) * DH];
#pragma unroll
            for (int it = 0; it < 4; it++) {
                int idx = it * 256 + t;
                int row = idx >> 3, c = idx & 7;
                *(short8*)&Ksh[row * 64 + (((c ^ (row & 7))) << 3)] =
                    *(const short8*)&Kg[row * DH + (c << 3)];
            }
            const short* Vg = &VT[bh * DH * S_ + base];
#pragma unroll
            for (int it = 0; it < 4; it++) {
                int idx = it * 256 + t;
                int d = idx >> 4, c = idx & 15;
                *(short8*)&Vsh[d * 128 + (((c ^ (d & 7))) << 3)] =
                    *(const short8*)&Vg[d * S_ + (c << 3)];
            }
        }
        __syncthreads();                             // staging visible

        // S^T: rows = key, col = q (l16)
        floatx4 sc[8];
#pragma unroll
        for (int n = 0; n < 8; n++) {
            int krow = n * 16 + l16;
            const short* kr = &Ksh[krow * 64];
            short8 kb0 = *(const short8*)&kr[((quad ^ (krow & 7)) << 3)];
            short8 kb1 = *(const short8*)&kr[(((4 + quad) ^ (krow & 7)) << 3)];
            floatx4 s = zero;
            s = mfma_s(kb0, qa0, s);
            s = mfma_s(kb1, qa1, s);
            sc[n] = s;
        }
        __syncthreads();                             // all Ksh reads done (P overlay)

        if (!bnd) {
#pragma unroll
            for (int n = 0; n < 8; n++)
#pragma unroll
                for (int r = 0; r < 4; r++) sc[n][r] *= SC;
        } else {
#pragma unroll
            for (int n = 0; n < 8; n++)
#pragma unroll
                for (int r = 0; r < 4; r++) {
                    int key = base + n * 16 + quad * 4 + r;
                    sc[n][r] = (key < vl) ? sc[n][r] * SC : -1e30f;
                }
        }

        // softmax (exp2 domain), per-lane q-column + 2 shuffles
        float mx = vmax4(sc[0]);
#pragma unroll
        for (int n = 1; n < 8; n++) mx = fmaxf(mx, vmax4(sc[n]));
        mx = fmaxf(mx, __shfl_xor(mx, 16));
        mx = fmaxf(mx, __shfl_xor(mx, 32));
        float mnew = fmaxf(m_run, mx);
        float alpha = __builtin_amdgcn_exp2f(m_run - mnew);
        m_run = mnew;
        float rs = 0.f;
#pragma unroll
        for (int n = 0; n < 8; n++)
#pragma unroll
            for (int r = 0; r < 4; r++) {
                float p = __builtin_amdgcn_exp2f(sc[n][r] - mnew);
                sc[n][r] = p;
                rs += p;
            }
        rs += __shfl_xor(rs, 16);
        rs += __shfl_xor(rs, 32);
        l_run = l_run * alpha + rs;
#pragma unroll
        for (int dt = 0; dt < 4; dt++)
#pragma unroll
            for (int r = 0; r < 4; r++) Oacc[dt][r] *= alpha;   // alpha lane-uniform

        // P^T store: 4 register-rows = 4 consecutive keys -> b64 writes
#pragma unroll
        for (int n = 0; n < 8; n++) {
            unsigned lo = pack2(sc[n][0], sc[n][1]);
            unsigned hi = pack2(sc[n][2], sc[n][3]);
            int c = (n << 1) + (quad >> 1);
            int idx = (w << 11) + (l16 << 7) + ((c ^ (l16 & 7)) << 3) + ((quad & 1) << 2);
            uint2v pv; pv[0] = lo; pv[1] = hi;
            *(uint2v*)&Psh[idx] = pv;
        }
        __syncthreads();                             // P visible + ordered

        // O^T += V^T * P^T
#pragma unroll
        for (int kk = 0; kk < 4; kk++) {
            int pc = (kk << 2) + quad;
            short8 pf = *(const short8*)&Psh[(w << 11) + (l16 << 7) + ((pc ^ (l16 & 7)) << 3)];
#pragma unroll
            for (int dt = 0; dt < 4; dt++) {
                int vrow = dt * 16 + l16;
                short8 vf = *(const short8*)&Vsh[vrow * 128 + ((pc ^ (vrow & 7)) << 3)];
                Oacc[dt] = mfma_s(vf, pf, Oacc[dt]);
            }
        }
    }

    // epilogue
    float inv = 1.0f / l_run;
    int q = qb + w * 16 + l16;
    short* dst = &AO[(b * S_ + q) * HIDN + h * DH];
#pragma unroll
    for (int dt = 0; dt < 4; dt++) {
        uint2v v;
        v[0] = pack2(Oacc[dt][0] * inv, Oacc[dt][1] * inv);
        v[1] = pack2(Oacc[dt][2] * inv, Oacc[dt][3] * inv);
        *(uint2v*)&dst[dt * 16 + quad * 4] = v;
    }
}

extern "C" void kernel_launch(void* const* d_in, const int* in_sizes, int n_in,
                              void* d_out, int out_size, void* d_ws, size_t ws_size,
                              hipStream_t stream) {
    const float* q  = (const float*)d_in[0];
    const float* k  = (const float*)d_in[1];
    const float* v  = (const float*)d_in[2];
    const int*   vl = (const int*)d_in[3];
    const float* wq = (const float*)d_in[4];
    const float* wk = (const float*)d_in[5];
    const float* wv = (const float*)d_in[6];
    const float* wo = (const float*)d_in[7];
    float* out = (float*)d_out;

    const size_t HSZ = (size_t)B_ * NH * S_ * DH;  // 4.19M shorts
    short* Qh  = (short*)d_ws;
    short* Kh  = Qh + HSZ;
    short* VT  = Kh + HSZ;
    short* AO  = VT + HSZ;
    short* Wqkv = AO;   // 3*256K shorts in the AO region (dead until attn)

    dim3 blk(256);
    cvt_w<<<dim3(256, 3), blk, 0, stream>>>(wq, wk, wv, Wqkv);
    gemm_qkv<<<dim3(64, 4, 3), blk, 0, stream>>>(q, k, v, Wqkv, Qh, Kh, VT);
    attn_kernel<<<dim3(1024), blk, 0, stream>>>(Qh, Kh, VT, vl, AO);
    gemm_out<<<dim3(64, 8), blk, 0, stream>>>(AO, wo, out);
}

// Round 6
// 173.049 us; speedup vs baseline: 1.1278x; 1.0060x over previous
//
#include <hip/hip_runtime.h>

#define B_ 4
#define S_ 2048
#define HIDN 512
#define NH 8
#define DH 64

typedef __attribute__((ext_vector_type(8))) short short8;
typedef __attribute__((ext_vector_type(4))) short short4v;
typedef __attribute__((ext_vector_type(8))) __bf16 bf16x8;
typedef __attribute__((ext_vector_type(4))) float floatx4;
typedef __attribute__((ext_vector_type(2))) unsigned uint2v;
typedef __attribute__((ext_vector_type(4))) unsigned uint4v;

__device__ inline short f2bf(float f) {            // RTNE
    union { float f; unsigned u; } x; x.f = f;
    unsigned r = x.u + 0x7fffu + ((x.u >> 16) & 1u);
    return (short)(r >> 16);
}

// pack two floats -> two bf16 (round-half-up) in one uint via v_perm
__device__ inline unsigned pack2(float a, float b) {
    unsigned ua = __builtin_bit_cast(unsigned, a) + 0x8000u;
    unsigned ub = __builtin_bit_cast(unsigned, b) + 0x8000u;
    return __builtin_amdgcn_perm(ub, ua, 0x07060302);  // shorts [a, b]
}

// 8 fp32 -> 8 bf16 (12 VALU)
__device__ inline short8 cvt8(const float* __restrict__ p) {
    floatx4 f0 = *(const floatx4*)p;
    floatx4 f1 = *(const floatx4*)(p + 4);
    uint4v u;
    u[0] = pack2(f0[0], f0[1]); u[1] = pack2(f0[2], f0[3]);
    u[2] = pack2(f1[0], f1[1]); u[3] = pack2(f1[2], f1[3]);
    return __builtin_bit_cast(short8, u);
}

__device__ inline floatx4 mfma_s(short8 a, short8 b, floatx4 c) {
    return __builtin_amdgcn_mfma_f32_16x16x32_bf16(
        __builtin_bit_cast(bf16x8, a), __builtin_bit_cast(bf16x8, b), c, 0, 0, 0);
}

__device__ inline float vmax4(floatx4 v) {
    return fmaxf(fmaxf(v[0], v[1]), fmaxf(v[2], v[3]));
}

// ---------------------------------------------------------------------------
// Pre-convert Wq,Wk,Wv (fp32 -> bf16). grid (256,3) x 256 thr, 4 elem/thr.
// ---------------------------------------------------------------------------
__global__ void cvt_w(const float* __restrict__ wq, const float* __restrict__ wk,
                      const float* __restrict__ wv, short* __restrict__ out) {
    const float* src = blockIdx.y == 0 ? wq : (blockIdx.y == 1 ? wk : wv);
    int i = (blockIdx.x * 256 + threadIdx.x) * 4;
    floatx4 f = *(const floatx4*)&src[i];
    short4v v; v[0]=f2bf(f[0]); v[1]=f2bf(f[1]); v[2]=f2bf(f[2]); v[3]=f2bf(f[3]);
    *(short4v*)&out[blockIdx.y * (HIDN * HIDN) + i] = v;
}

// ---------------------------------------------------------------------------
// Fused QKV projection (round-0 verbatim). grid (64,4,3); z=0:Q, z=1:K,
// z=2:V^T. r4 2D-padded idiom, BK=64. X fp32 cvt in staging; W bf16.
// ---------------------------------------------------------------------------
__global__ __launch_bounds__(256) void gemm_qkv(const float* __restrict__ xq,
                                                const float* __restrict__ xk,
                                                const float* __restrict__ xv,
                                                const short* __restrict__ wb,
                                                short* __restrict__ Qh,
                                                short* __restrict__ Kh,
                                                short* __restrict__ VT) {
    const int z = blockIdx.z;
    const float* X = z == 0 ? xq : (z == 1 ? xk : xv);
    const short* W = wb + z * (HIDN * HIDN);
    short* dstQK = z == 0 ? Qh : Kh;

    __shared__ __align__(16) short Als[128][72];   // 64 cols + pad to 72
    __shared__ __align__(16) short Bls[128][72];

    const int t = threadIdx.x;
    const int w = t >> 6, lane = t & 63, quad = lane >> 4, l16 = lane & 15;
    const int wm = (w & 1) * 64, wn = (w >> 1) * 64;
    const int m0 = blockIdx.x * 128, n0 = blockIdx.y * 128;

    floatx4 acc[4][4];
    floatx4 zero = {0.f, 0.f, 0.f, 0.f};
#pragma unroll
    for (int i = 0; i < 4; i++)
#pragma unroll
        for (int j = 0; j < 4; j++) acc[i][j] = zero;

    const int row0 = t >> 3;        // 0..31
    const int c8 = (t & 7) * 8;     // 0..56

    for (int k0 = 0; k0 < HIDN; k0 += 64) {
        __syncthreads();
#pragma unroll
        for (int rr = 0; rr < 4; rr++)
            *(short8*)&Als[row0 + rr*32][c8] =
                cvt8(&X[(m0 + row0 + rr*32) * HIDN + k0 + c8]);
#pragma unroll
        for (int rr = 0; rr < 4; rr++)
            *(short8*)&Bls[row0 + rr*32][c8] =
                *(const short8*)&W[(n0 + row0 + rr*32) * HIDN + k0 + c8];
        __syncthreads();

#pragma unroll
        for (int ks = 0; ks < 2; ks++) {
            const int cq8 = (ks * 4 + quad) * 8;
            short8 a[4], b[4];
#pragma unroll
            for (int i = 0; i < 4; i++)
                a[i] = *(const short8*)&Als[wm + i*16 + l16][cq8];
#pragma unroll
            for (int j = 0; j < 4; j++)
                b[j] = *(const short8*)&Bls[wn + j*16 + l16][cq8];
#pragma unroll
            for (int i = 0; i < 4; i++)
#pragma unroll
                for (int j = 0; j < 4; j++)
                    acc[i][j] = mfma_s(a[i], b[j], acc[i][j]);
        }
    }

    if (z < 2) {   // head layout (B,NH,S,DH)
#pragma unroll
        for (int i = 0; i < 4; i++)
#pragma unroll
            for (int j = 0; j < 4; j++)
#pragma unroll
                for (int r = 0; r < 4; r++) {
                    int m = m0 + wm + i*16 + quad*4 + r;
                    int n = n0 + wn + j*16 + l16;
                    int bb = m >> 11, s = m & 2047, h = n >> 6, d = n & 63;
                    dstQK[((bb * NH + h) * S_ + s) * DH + d] = f2bf(acc[i][j][r]);
                }
    } else {       // V^T (B,NH,DH,S)
#pragma unroll
        for (int i = 0; i < 4; i++)
#pragma unroll
            for (int j = 0; j < 4; j++) {
                int s0 = m0 + wm + i*16 + quad*4;
                int n = n0 + wn + j*16 + l16;
                int bb = s0 >> 11, s = s0 & 2047, h = n >> 6, d = n & 63;
                uint2v v;
                v[0] = pack2(acc[i][j][0], acc[i][j][1]);
                v[1] = pack2(acc[i][j][2], acc[i][j][3]);
                *(uint2v*)&VT[((bb * NH + h) * DH + d) * S_ + s] = v;
            }
    }
}

// ---------------------------------------------------------------------------
// Out projection (round-0 verbatim). 128x64 tile, grid(64,8), BK=64 padded.
// ---------------------------------------------------------------------------
__global__ __launch_bounds__(256) void gemm_out(const short* __restrict__ AO,
                                                const float* __restrict__ Wo,
                                                float* __restrict__ C) {
    __shared__ __align__(16) short Als[128][72];
    __shared__ __align__(16) short Bls[64][72];

    const int t = threadIdx.x;
    const int w = t >> 6, lane = t & 63, quad = lane >> 4, l16 = lane & 15;
    const int wm = (w & 1) * 64, wn = (w >> 1) * 32;
    const int m0 = blockIdx.x * 128, n0 = blockIdx.y * 64;

    floatx4 acc[4][2];
    floatx4 zero = {0.f, 0.f, 0.f, 0.f};
#pragma unroll
    for (int i = 0; i < 4; i++)
#pragma unroll
        for (int j = 0; j < 2; j++) acc[i][j] = zero;

    const int row0 = t >> 3;        // 0..31
    const int c8 = (t & 7) * 8;     // 0..56

    for (int k0 = 0; k0 < HIDN; k0 += 64) {
        __syncthreads();
#pragma unroll
        for (int rr = 0; rr < 4; rr++)
            *(short8*)&Als[row0 + rr*32][c8] =
                *(const short8*)&AO[(m0 + row0 + rr*32) * HIDN + k0 + c8];
#pragma unroll
        for (int rr = 0; rr < 2; rr++)
            *(short8*)&Bls[row0 + rr*32][c8] =
                cvt8(&Wo[(n0 + row0 + rr*32) * HIDN + k0 + c8]);
        __syncthreads();

#pragma unroll
        for (int ks = 0; ks < 2; ks++) {
            const int cq8 = (ks * 4 + quad) * 8;
            short8 a[4], b[2];
#pragma unroll
            for (int i = 0; i < 4; i++)
                a[i] = *(const short8*)&Als[wm + i*16 + l16][cq8];
#pragma unroll
            for (int j = 0; j < 2; j++)
                b[j] = *(const short8*)&Bls[wn + j*16 + l16][cq8];
#pragma unroll
            for (int i = 0; i < 4; i++)
#pragma unroll
                for (int j = 0; j < 2; j++)
                    acc[i][j] = mfma_s(a[i], b[j], acc[i][j]);
        }
    }

#pragma unroll
    for (int i = 0; i < 4; i++)
#pragma unroll
        for (int j = 0; j < 2; j++)
#pragma unroll
            for (int r = 0; r < 4; r++) {
                int m = m0 + wm + i*16 + quad*4 + r;
                int n = n0 + wn + j*16 + l16;
                C[m * HIDN + n] = acc[i][j][r];
            }
}

// ---------------------------------------------------------------------------
// Flash attention — round-5 (h-clustered XCD swizzle, FETCH 41->10 MB proven)
// + the three resource-neutral VALU/barrier trims from round 1 (correctness-
// validated there, perf-confounded by a prefetch spill now absent):
//   1. SC folded into exp2 via fmaf (kills the 32-mult scale pass; mask in
//      raw domain — monotone under SC>0, masked fmaf still -> exp2(-huge)=0)
//   2. T13: __all-skip of the Oacc rescale when tile max doesn't raise m_run
//   3. barrier #4 -> wave-local s_waitcnt lgkmcnt(0) + sched_barrier
//      (P region is written and read only by the owning wave)
// Body otherwise round-0 verbatim. 2 block barriers + 1 wave fence per tile.
// ---------------------------------------------------------------------------
__global__ __launch_bounds__(256, 4) void attn_kernel(const short* __restrict__ Qh,
                                                      const short* __restrict__ Kh,
                                                      const short* __restrict__ VT,
                                                      const int* __restrict__ vlen,
                                                      short* __restrict__ AO) {
    __shared__ __align__(16) short Ksh[128 * 64];   // K tile; overlaid by P
    __shared__ __align__(16) short Vsh[64 * 128];   // V^T tile
    short* Psh = Ksh;                                // wave w region: w*2048 shorts

    const int t = threadIdx.x, w = t >> 6, lane = t & 63;
    const int quad = lane >> 4, l16 = lane & 15;

    // XCD swizzle: orig%8 -> XCD; make that the head index.
    const int orig = blockIdx.x;                     // 0..1023
    const int wgid = ((orig & 7) << 7) + (orig >> 3);
    const int h = wgid >> 7;                         // 0..7  (== orig%8 == XCD)
    const int rem = wgid & 127;
    const int b = rem >> 5;                          // 0..3
    const int qb = (rem & 31) * 64;                  // q-tile
    const int bh = b * NH + h;
    const int vl = vlen[b];
    const int nfull = vl >> 7, rem128 = vl & 127;
    const int nt = nfull + (rem128 ? 1 : 0);

    const float SC = 0.180336879f;                   // 0.125 * log2(e)

    const short* qrow = &Qh[(bh * S_ + qb + w * 16 + l16) * DH];
    short8 qa0 = *(const short8*)&qrow[quad * 8];
    short8 qa1 = *(const short8*)&qrow[32 + quad * 8];

    float m_run = -1e30f, l_run = 0.f;
    floatx4 Oacc[4];
    floatx4 zero = {0.f, 0.f, 0.f, 0.f};
#pragma unroll
    for (int dt = 0; dt < 4; dt++) Oacc[dt] = zero;

    for (int kt = 0; kt < nt; kt++) {
        const int base = kt << 7;
        const bool bnd = (base + 128) > vl;
        __syncthreads();                             // #1: prev PV reads done
        {
            const short* Kg = &Kh[(bh * S_ + base) * DH];
#pragma unroll
            for (int it = 0; it < 4; it++) {
                int idx = it * 256 + t;
                int row = idx >> 3, c = idx & 7;
                *(short8*)&Ksh[row * 64 + (((c ^ (row & 7))) << 3)] =
                    *(const short8*)&Kg[row * DH + (c << 3)];
            }
            const short* Vg = &VT[bh * DH * S_ + base];
#pragma unroll
            for (int it = 0; it < 4; it++) {
                int idx = it * 256 + t;
                int d = idx >> 4, c = idx & 15;
                *(short8*)&Vsh[d * 128 + (((c ^ (d & 7))) << 3)] =
                    *(const short8*)&Vg[d * S_ + (c << 3)];
            }
        }
        __syncthreads();                             // #2: staging visible

        // S^T: rows = key, col = q (l16)
        floatx4 sc[8];
#pragma unroll
        for (int n = 0; n < 8; n++) {
            int krow = n * 16 + l16;
            const short* kr = &Ksh[krow * 64];
            short8 kb0 = *(const short8*)&kr[((quad ^ (krow & 7)) << 3)];
            short8 kb1 = *(const short8*)&kr[(((4 + quad) ^ (krow & 7)) << 3)];
            floatx4 s = zero;
            s = mfma_s(kb0, qa0, s);
            s = mfma_s(kb1, qa1, s);
            sc[n] = s;
        }
        __syncthreads();                             // #3: Ksh reads done (P overlay)

        // mask in RAW domain (SC > 0, so max commutes with scaling)
        if (bnd) {
#pragma unroll
            for (int n = 0; n < 8; n++)
#pragma unroll
                for (int r = 0; r < 4; r++) {
                    int key = base + n * 16 + quad * 4 + r;
                    if (key >= vl) sc[n][r] = -1e30f;
                }
        }

        // softmax (exp2 domain), per-lane q-column + 2 shuffles
        float mx = vmax4(sc[0]);
#pragma unroll
        for (int n = 1; n < 8; n++) mx = fmaxf(mx, vmax4(sc[n]));
        mx = fmaxf(mx, __shfl_xor(mx, 16));
        mx = fmaxf(mx, __shfl_xor(mx, 32));
        const float mxs = mx * SC;
        const bool norescale = __all(mxs <= m_run);
        const float mnew = norescale ? m_run : fmaxf(m_run, mxs);
        const float alpha = norescale ? 1.0f : __builtin_amdgcn_exp2f(m_run - mnew);
        m_run = mnew;
        float rs = 0.f;
#pragma unroll
        for (int n = 0; n < 8; n++)
#pragma unroll
            for (int r = 0; r < 4; r++) {
                float p = __builtin_amdgcn_exp2f(fmaf(sc[n][r], SC, -mnew));
                sc[n][r] = p;
                rs += p;
            }
        rs += __shfl_xor(rs, 16);
        rs += __shfl_xor(rs, 32);
        l_run = l_run * alpha + rs;
        if (!norescale) {
#pragma unroll
            for (int dt = 0; dt < 4; dt++)
#pragma unroll
                for (int r = 0; r < 4; r++) Oacc[dt][r] *= alpha;
        }

        // P^T store: 4 register-rows = 4 consecutive keys -> b64 writes
#pragma unroll
        for (int n = 0; n < 8; n++) {
            unsigned lo = pack2(sc[n][0], sc[n][1]);
            unsigned hi = pack2(sc[n][2], sc[n][3]);
            int c = (n << 1) + (quad >> 1);
            int idx = (w << 11) + (l16 << 7) + ((c ^ (l16 & 7)) << 3) + ((quad & 1) << 2);
            uint2v pv; pv[0] = lo; pv[1] = hi;
            *(uint2v*)&Psh[idx] = pv;
        }
        // P is wave-local (own region, own reads): no block barrier needed.
        asm volatile("s_waitcnt lgkmcnt(0)" ::: "memory");
        __builtin_amdgcn_sched_barrier(0);

        // O^T += V^T * P^T
#pragma unroll
        for (int kk = 0; kk < 4; kk++) {
            int pc = (kk << 2) + quad;
            short8 pf = *(const short8*)&Psh[(w << 11) + (l16 << 7) + ((pc ^ (l16 & 7)) << 3)];
#pragma unroll
            for (int dt = 0; dt < 4; dt++) {
                int vrow = dt * 16 + l16;
                short8 vf = *(const short8*)&Vsh[vrow * 128 + ((pc ^ (vrow & 7)) << 3)];
                Oacc[dt] = mfma_s(vf, pf, Oacc[dt]);
            }
        }
    }

    // epilogue
    float inv = 1.0f / l_run;
    int q = qb + w * 16 + l16;
    short* dst = &AO[(b * S_ + q) * HIDN + h * DH];
#pragma unroll
    for (int dt = 0; dt < 4; dt++) {
        uint2v v;
        v[0] = pack2(Oacc[dt][0] * inv, Oacc[dt][1] * inv);
        v[1] = pack2(Oacc[dt][2] * inv, Oacc[dt][3] * inv);
        *(uint2v*)&dst[dt * 16 + quad * 4] = v;
    }
}

extern "C" void kernel_launch(void* const* d_in, const int* in_sizes, int n_in,
                              void* d_out, int out_size, void* d_ws, size_t ws_size,
                              hipStream_t stream) {
    const float* q  = (const float*)d_in[0];
    const float* k  = (const float*)d_in[1];
    const float* v  = (const float*)d_in[2];
    const int*   vl = (const int*)d_in[3];
    const float* wq = (const float*)d_in[4];
    const float* wk = (const float*)d_in[5];
    const float* wv = (const float*)d_in[6];
    const float* wo = (const float*)d_in[7];
    float* out = (float*)d_out;

    const size_t HSZ = (size_t)B_ * NH * S_ * DH;  // 4.19M shorts
    short* Qh  = (short*)d_ws;
    short* Kh  = Qh + HSZ;
    short* VT  = Kh + HSZ;
    short* AO  = VT + HSZ;
    short* Wqkv = AO;   // 3*256K shorts in the AO region (dead until attn)

    dim3 blk(256);
    cvt_w<<<dim3(256, 3), blk, 0, stream>>>(wq, wk, wv, Wqkv);
    gemm_qkv<<<dim3(64, 4, 3), blk, 0, stream>>>(q, k, v, Wqkv, Qh, Kh, VT);
    attn_kernel<<<dim3(1024), blk, 0, stream>>>(Qh, Kh, VT, vl, AO);
    gemm_out<<<dim3(64, 8), blk, 0, stream>>>(AO, wo, out);
}